// Round 8
// baseline (32.980 us; speedup 1.0000x reference)
//
#include <hip/hip_runtime.h>
#include <math.h>
#include <stdint.h>

#define HH 128
#define WW 128
#define LROWS 36
#define ROWU 72              // u32 per LDS row = 144 f16 (8-col halo each side)
#define UNITS 648            // 36 rows * 18 16B-units per row
#define LDSU (LROWS * ROWU)  // 2592 u32 = 10368 B

typedef __fp16 h2 __attribute__((ext_vector_type(2)));

__device__ __forceinline__ h2 h2max(h2 a, h2 b) { return __builtin_elementwise_max(a, b); }
__device__ __forceinline__ uint32_t h2u(h2 v) { return __builtin_bit_cast(uint32_t, v); }
__device__ __forceinline__ h2 uh2(uint32_t v) { return __builtin_bit_cast(h2, v); }

__global__ __launch_bounds__(256, 6) void morpho_kernel(
    const float* __restrict__ x,     // [B,C,128,128]
    const float* __restrict__ wgt,   // [B,C,5,5]
    const float* __restrict__ bias,  // [B,C]
    const float* __restrict__ sign,  // [B]
    float* __restrict__ out)         // [B,C,128,128]
{
    __shared__ uint32_t lds[LDSU];

    const int blk  = blockIdx.x;
    const int quad = blk & 3;        // 32-row band
    const int bc   = blk >> 2;       // plane = b*64 + c
    const int b    = bc >> 6;

    const float* __restrict__ xp = x   + (size_t)bc * (HH * WW);
    float*       __restrict__ yp = out + (size_t)bc * (HH * WW);
    const float* __restrict__ wp = wgt + bc * 25;

    const float sgn = sign[b];
    const float s   = (fabsf(sgn) >= 1e-7f) ? sgn : 1.0f;
    const float bvs = bias[bc] * s;
    const __fp16 sh = (__fp16)s;
    const h2 s2 = { sh, sh };
    const h2 z2 = { (__fp16)0.f, (__fp16)0.f };

    const int t = threadIdx.x;

    // ---- T14 phase 1: issue all staging loads (unconditional, clamped) ----
    // unit u = t + k*256 covers LDS 16B-unit (row = u/18, uc = u%18);
    // global cols 8*uc-8 .. 8*uc-1 of input row quad*32-2+row.
    float4 v0[3], v1[3];
    int urow[3], uuc[3];
    bool uin[3], uivalid[3];
#pragma unroll
    for (int k = 0; k < 3; ++k) {
        const int u   = t + k * 256;
        uin[k]        = (u < UNITS);
        const int row = u / 18;
        const int uc  = u - row * 18;
        urow[k] = row;  uuc[k] = uc;
        const int grow = quad * 32 - 2 + row;
        uivalid[k] = uin[k] && (uc >= 1) && (uc <= 16) && ((unsigned)grow < (unsigned)HH);
        const int rc = min(max(grow, 0), HH - 1);
        const int cc = min(max(uc * 8 - 8, 0), WW - 8);
        const float* gp = xp + rc * WW + cc;
        v0[k] = *reinterpret_cast<const float4*>(gp);
        v1[k] = *reinterpret_cast<const float4*>(gp + 4);
    }

    // ---- weight prep under load latency: f16 broadcast pairs -> SGPRs ----
    int ws[25];
#pragma unroll
    for (int k = 0; k < 25; ++k) {
        const __fp16 wh = (__fp16)wp[k];
        h2 wv2 = { wh, wh };
        ws[k] = __builtin_amdgcn_readfirstlane((int)h2u(wv2));
    }

    // ---- T14 phase 2: cvt to f16, scale by s (mask pads to 0), LDS write ----
#pragma unroll
    for (int k = 0; k < 3; ++k) {
        if (uin[k]) {
            const h2 m = uivalid[k] ? s2 : z2;
            const h2 h0 = __builtin_amdgcn_cvt_pkrtz(v0[k].x, v0[k].y) * m;
            const h2 h1 = __builtin_amdgcn_cvt_pkrtz(v0[k].z, v0[k].w) * m;
            const h2 hv = __builtin_amdgcn_cvt_pkrtz(v1[k].x, v1[k].y) * m;
            const h2 h3 = __builtin_amdgcn_cvt_pkrtz(v1[k].z, v1[k].w) * m;
            uint4 o;
            o.x = h2u(h0); o.y = h2u(h1); o.z = h2u(hv); o.w = h2u(h3);
            *reinterpret_cast<uint4*>(&lds[urow[k] * ROWU + uuc[k] * 4]) = o;
        }
    }

    __syncthreads();

    // ---- compute: 4 rows x 4 cols per thread, packed f16 (2 cols/inst) ----
    const int tx = t & 31;
    const int ty = t >> 5;
    h2 acc0[4], acc1[4];             // pair0 = cols j0,j0+1; pair1 = j0+2,j0+3

#pragma unroll
    for (int r8 = 0; r8 < 8; ++r8) {
        // f16 idx of col c is c+8; u32 slot i holds cols (2i-8, 2i-7)
        const uint32_t* lp = &lds[(ty * 4 + r8) * ROWU + 2 * tx + 2];
        const uint32_t r1 = lp[1];
        const uint2   d23 = *reinterpret_cast<const uint2*>(lp + 2);
        const uint32_t r2 = d23.x, r3 = d23.y;
        const uint32_t r4 = lp[4];
        const uint32_t am1 = __builtin_amdgcn_alignbit(r2, r1, 16); // cols (j0-1,j0)
        const uint32_t a1  = __builtin_amdgcn_alignbit(r3, r2, 16); // cols (j0+1,j0+2)
        const uint32_t a3  = __builtin_amdgcn_alignbit(r4, r3, 16); // cols (j0+3,j0+4)
        const uint32_t P0a[5] = { r1, am1, r2, a1, r3 };  // pair0 taps q=0..4
        const uint32_t P1a[5] = { r2, a1, r3, a3, r4 };   // pair1 taps q=0..4

#pragma unroll
        for (int p = 0; p < 5; ++p) {
            const int oi = r8 - p;
            if (oi >= 0 && oi < 4) {
                // pair0
                {
                    const h2 t0 = uh2(P0a[0]) + uh2((uint32_t)ws[p * 5 + 0]);
                    const h2 t1 = uh2(P0a[1]) + uh2((uint32_t)ws[p * 5 + 1]);
                    const h2 t2 = uh2(P0a[2]) + uh2((uint32_t)ws[p * 5 + 2]);
                    const h2 t3 = uh2(P0a[3]) + uh2((uint32_t)ws[p * 5 + 3]);
                    const h2 t4 = uh2(P0a[4]) + uh2((uint32_t)ws[p * 5 + 4]);
                    h2 mm = h2max(h2max(h2max(t0, t1), h2max(t2, t3)), t4);
                    acc0[oi] = (p == 0) ? mm : h2max(acc0[oi], mm);
                }
                // pair1
                {
                    const h2 t0 = uh2(P1a[0]) + uh2((uint32_t)ws[p * 5 + 0]);
                    const h2 t1 = uh2(P1a[1]) + uh2((uint32_t)ws[p * 5 + 1]);
                    const h2 t2 = uh2(P1a[2]) + uh2((uint32_t)ws[p * 5 + 2]);
                    const h2 t3 = uh2(P1a[3]) + uh2((uint32_t)ws[p * 5 + 3]);
                    const h2 t4 = uh2(P1a[4]) + uh2((uint32_t)ws[p * 5 + 4]);
                    h2 mm = h2max(h2max(h2max(t0, t1), h2max(t2, t3)), t4);
                    acc1[oi] = (p == 0) ? mm : h2max(acc1[oi], mm);
                }
            }
        }
    }

    // ---- epilogue: y = acc*s + bias*s in f32 ----
    const int i0 = quad * 32 + ty * 4;
    const int j0 = tx * 4;
#pragma unroll
    for (int a = 0; a < 4; ++a) {
        float4 o;
        o.x = fmaf((float)acc0[a][0], s, bvs);
        o.y = fmaf((float)acc0[a][1], s, bvs);
        o.z = fmaf((float)acc1[a][0], s, bvs);
        o.w = fmaf((float)acc1[a][1], s, bvs);
        *reinterpret_cast<float4*>(yp + (size_t)(i0 + a) * WW + j0) = o;
    }
}

extern "C" void kernel_launch(void* const* d_in, const int* in_sizes, int n_in,
                              void* d_out, int out_size, void* d_ws, size_t ws_size,
                              hipStream_t stream) {
    (void)d_ws; (void)ws_size; (void)in_sizes; (void)n_in; (void)out_size;
    const float* x    = (const float*)d_in[0];
    const float* w    = (const float*)d_in[1];
    const float* bias = (const float*)d_in[2];
    const float* sign = (const float*)d_in[3];
    float* out = (float*)d_out;

    morpho_kernel<<<4096, 256, 0, stream>>>(x, w, bias, sign, out);
}